// Round 3
// baseline (453.524 us; speedup 1.0000x reference)
//
#include <hip/hip_runtime.h>
#include <hip/hip_bf16.h>

// y[m, p*32+q] = sum_{r,s} x[m, r*32+s] * W2[p,r] * W1[q,s] + bias[p*32+q]
//   == (W2 · X_m · W1^T)[p,q],  X_m = reshape(x[m], 32, 32)
//
// One wave per row m, TWO rows per loop iteration with interleaved
// independent chains (ILP) and next-pair register prefetch (MLP).
// Stage 1: T = X·W1^T. Stage 2 (transposed): C[q][p] = sum_r T[r][q]·W2[p][r],
// T-fragment rebuilt in-register via v_cvt_pk_bf16_f32 (+permlane32_swap).
// Bias preloaded as the stage-2 accumulator init. No LDS.

typedef short bf16x8 __attribute__((ext_vector_type(8)));   // 8 bf16 = 4 VGPRs
typedef float f32x16 __attribute__((ext_vector_type(16)));  // C/D acc
typedef float f32x4  __attribute__((ext_vector_type(4)));
typedef unsigned uint32x2 __attribute__((ext_vector_type(2)));
typedef unsigned uint32x4 __attribute__((ext_vector_type(4)));

#define MFMA32(A, B, C) __builtin_amdgcn_mfma_f32_32x32x16_bf16((A), (B), (C), 0, 0, 0)

// two f32 -> one dword of two bf16 (RNE); intrinsic form so the scheduler
// can move/fuse it freely (m240: hand-asm cvt_pk blocks scheduling)
__device__ __forceinline__ unsigned pk2(float lo, float hi) {
    float2 f; f.x = lo; f.y = hi;
    __hip_bfloat162 b = __float22bfloat162_rn(f);
    unsigned r;
    __builtin_memcpy(&r, &b, 4);   // bit move; __hip_bfloat162 not trivially copyable
    return r;
}

// fp32 -> bf16 RNE (loop-invariant weight fragments only)
__device__ __forceinline__ short f2bf(float f) {
    unsigned u = __builtin_bit_cast(unsigned, f);
    u = (u + 0x7fffu + ((u >> 16) & 1u)) >> 16;
    return (short)u;
}

constexpr int M_TOTAL = 8 * 8192;   // 65536 rows of 1024
constexpr int BLOCKS  = 2048;
constexpr int TPB     = 256;        // 4 waves/block
constexpr int NWAVES  = BLOCKS * (TPB / 64);   // 8192 waves
constexpr int RPW     = M_TOTAL / NWAVES;      // 8 rows/wave (even)

struct RowData { f32x4 a, b, c, d; };

__device__ __forceinline__ RowData load_row(const float* p) {
    RowData r;
    r.a = *(const f32x4*)(p + 0);
    r.b = *(const f32x4*)(p + 4);
    r.c = *(const f32x4*)(p + 16);
    r.d = *(const f32x4*)(p + 20);
    return r;
}

__global__ __launch_bounds__(TPB, 4) void kron_mlp_kernel(
    const float* __restrict__ x,    // (65536, 1024)
    const float* __restrict__ w1,   // (32, 32): W1[q][s]
    const float* __restrict__ w2,   // (32, 32): W2[p][r]
    const float* __restrict__ bias, // (1024,)
    float* __restrict__ out)        // (65536, 1024)
{
    const int tid  = threadIdx.x;
    const int wid  = tid >> 6;
    const int lane = tid & 63;
    const int c    = lane & 31;   // stage1: A row / B col.  stage2: B col p.
    const int h    = lane >> 5;   // half-wave k-range selector

    // ---- loop-invariant fragments ----
    // Stage-1 B (W1^T): element[k=8h+j][n=c] = W1[c][8h+j]   (b1: +16)
    // Stage-2 B (W2 as B[r][p]=W2[p][r]):   element[k=8h+j][n=c] = W2[c][8h+j]
    bf16x8 w1b0, w1b1, w2b0, w2b1;
    {
        const float* p1 = w1 + c * 32 + 8 * h;
        const float* p2 = w2 + c * 32 + 8 * h;
        #pragma unroll
        for (int j = 0; j < 8; ++j) {
            w1b0[j] = f2bf(p1[j]);  w1b1[j] = f2bf(p1[16 + j]);
            w2b0[j] = f2bf(p2[j]);  w2b1[j] = f2bf(p2[16 + j]);
        }
    }

    // Stage-2 C-init = bias. C/D: col=p=c, row=q=(reg&3)+8*(reg>>2)+4h,
    // y-index = p*32+q -> reg 4g+i corresponds to bias[c*32 + 8g + 4h + i].
    f32x16 yinit;
    #pragma unroll
    for (int g = 0; g < 4; ++g) {
        const f32x4 b4 = *(const f32x4*)(bias + c * 32 + 8 * g + 4 * h);
        yinit[4 * g + 0] = b4[0]; yinit[4 * g + 1] = b4[1];
        yinit[4 * g + 2] = b4[2]; yinit[4 * g + 3] = b4[3];
    }

    const int    gwave   = blockIdx.x * (TPB / 64) + wid;
    const size_t RSTRIDE = (size_t)NWAVES * 1024;   // row k -> row k+1 (per wave)

    const float* xp = x   + (size_t)gwave * 1024 + c * 32 + 8 * h;
    float*       op = out + (size_t)gwave * 1024 + c * 32 + 4 * h;

    // Single row: pk -> stage1 -> in-register relayout -> stage2 -> store.
    // In-register re-layout: lane (c,h') reg r holds T[(r&3)+8*(r>>2)+4h'][c];
    // stage-2 A fragment needs tb0[j]=T[8h+j][c], tb1[j]=T[16+8h+j][c].
    // permlane32_swap(A,B): new_A = {A.lo31, B.lo31}, new_B = {A.hi31, B.hi31}.
    auto run_row = [&](const RowData& R, float* o) {
        uint32x4 ua = { pk2(R.a[0], R.a[1]), pk2(R.a[2], R.a[3]),
                        pk2(R.b[0], R.b[1]), pk2(R.b[2], R.b[3]) };
        uint32x4 ub = { pk2(R.c[0], R.c[1]), pk2(R.c[2], R.c[3]),
                        pk2(R.d[0], R.d[1]), pk2(R.d[2], R.d[3]) };

        f32x16 t = {};
        t = MFMA32(__builtin_bit_cast(bf16x8, ua), w1b0, t);
        t = MFMA32(__builtin_bit_cast(bf16x8, ub), w1b1, t);

        uint32x2 r0 = __builtin_amdgcn_permlane32_swap(pk2(t[0],  t[1]),  pk2(t[4],  t[5]),  false, false);
        uint32x2 r1 = __builtin_amdgcn_permlane32_swap(pk2(t[2],  t[3]),  pk2(t[6],  t[7]),  false, false);
        uint32x2 r2 = __builtin_amdgcn_permlane32_swap(pk2(t[8],  t[9]),  pk2(t[12], t[13]), false, false);
        uint32x2 r3 = __builtin_amdgcn_permlane32_swap(pk2(t[10], t[11]), pk2(t[14], t[15]), false, false);
        uint32x4 utb0 = { r0[0], r1[0], r0[1], r1[1] };
        uint32x4 utb1 = { r2[0], r3[0], r2[1], r3[1] };

        f32x16 yv = yinit;
        yv = MFMA32(__builtin_bit_cast(bf16x8, utb0), w2b0, yv);
        yv = MFMA32(__builtin_bit_cast(bf16x8, utb1), w2b1, yv);

        #pragma unroll
        for (int g = 0; g < 4; ++g) {
            f32x4 ov = { yv[4 * g + 0], yv[4 * g + 1],
                         yv[4 * g + 2], yv[4 * g + 3] };
            *(f32x4*)(o + g * 8) = ov;
        }
    };

    // Two independent rows back-to-back in one straight-line region: the
    // scheduler interleaves the two chains (no dependent MFMA pairs, pk/perm
    // latency of row0 hides under row1 and vice versa).
    auto run_pair = [&](const RowData& R0, const RowData& R1,
                        float* o0, float* o1) {
        run_row(R0, o0);
        run_row(R1, o1);
    };

    // ---- pair-wise main loop, next-pair register prefetch (8 KiB/wave) ----
    RowData r0 = load_row(xp);
    RowData r1 = load_row(xp + RSTRIDE);

    #pragma unroll 1
    for (int it = 0; it < RPW / 2 - 1; ++it) {
        const float* nxt = xp + 2 * RSTRIDE;
        RowData n0 = load_row(nxt);
        RowData n1 = load_row(nxt + RSTRIDE);
        run_pair(r0, r1, op, op + RSTRIDE);
        r0 = n0; r1 = n1;
        xp = nxt; op += 2 * RSTRIDE;
    }
    run_pair(r0, r1, op, op + RSTRIDE);
}

extern "C" void kernel_launch(void* const* d_in, const int* in_sizes, int n_in,
                              void* d_out, int out_size, void* d_ws, size_t ws_size,
                              hipStream_t stream) {
    const float* x    = (const float*)d_in[0];
    const float* w1   = (const float*)d_in[1];
    const float* w2   = (const float*)d_in[2];
    const float* bias = (const float*)d_in[3];
    float* out        = (float*)d_out;
    kron_mlp_kernel<<<dim3(BLOCKS), dim3(TPB), 0, stream>>>(x, w1, w2, bias, out);
}

// Round 4
// 433.756 us; speedup vs baseline: 1.0456x; 1.0456x over previous
//
#include <hip/hip_runtime.h>

// y[m, p*32+q] = sum_{r,s} x[m, r*32+s] * W2[p,r] * W1[q,s] + bias[p*32+q]
//   == (W2 · X_m · W1^T)[p,q],  X_m = reshape(x[m], 32, 32)
//
// One wave per row m. Stage 1: T = X·W1^T (2x mfma_32x32x16_bf16).
// Stage 2 in ROUND-0 ORIENTATION (Y = W2·T, W2 as A) so the epilogue is
// 128B-coalesced scalar stores, but the T B-fragment is rebuilt entirely
// in-register via v_cvt_pk_bf16_f32 + permlane32_swap (no LDS round-trip).
// Bias preloaded into the stage-2 accumulator (C operand). 1-row prefetch.

typedef short bf16x8 __attribute__((ext_vector_type(8)));   // 8 bf16 = 4 VGPRs
typedef float f32x16 __attribute__((ext_vector_type(16)));  // C/D acc
typedef float f32x4  __attribute__((ext_vector_type(4)));
typedef unsigned uint32x2 __attribute__((ext_vector_type(2)));
typedef unsigned uint32x4 __attribute__((ext_vector_type(4)));

#define MFMA32(A, B, C) __builtin_amdgcn_mfma_f32_32x32x16_bf16((A), (B), (C), 0, 0, 0)

// fp32 -> bf16 RNE (same rounding as v_cvt_pk_bf16_f32; NaN irrelevant here)
__device__ __forceinline__ short f2bf(float f) {
    unsigned u = __builtin_bit_cast(unsigned, f);
    u = (u + 0x7fffu + ((u >> 16) & 1u)) >> 16;
    return (short)u;
}

// two f32 -> one dword of two bf16 (RNE), low = lo, high = hi
__device__ __forceinline__ unsigned pk2(float lo, float hi) {
    return (unsigned)(unsigned short)f2bf(lo) | ((unsigned)(unsigned short)f2bf(hi) << 16);
}

constexpr int M_TOTAL = 8 * 8192;   // 65536 rows of 1024
constexpr int BLOCKS  = 2048;
constexpr int TPB     = 256;        // 4 waves/block
constexpr int NWAVES  = BLOCKS * (TPB / 64);   // 8192 waves
constexpr int RPW     = M_TOTAL / NWAVES;      // 8 rows/wave

__global__ __launch_bounds__(TPB) void kron_mlp_kernel(
    const float* __restrict__ x,    // (65536, 1024)
    const float* __restrict__ w1,   // (32, 32): W1[q][s]
    const float* __restrict__ w2,   // (32, 32): W2[p][r]
    const float* __restrict__ bias, // (1024,)
    float* __restrict__ out)        // (65536, 1024)
{
    const int tid  = threadIdx.x;
    const int wid  = tid >> 6;
    const int lane = tid & 63;
    const int c    = lane & 31;   // A row / B col index
    const int h    = lane >> 5;   // half-wave k-range selector

    // ---- loop-invariant fragments ----
    // Stage-1 B (W1^T): element[k=8h+j][n=c] = W1[c][8h+j]   (b1: +16)
    // Stage-2 A (W2):   element[m=c][k=8h+j] = W2[c][8h+j]   (a1: +16)
    bf16x8 w1b0, w1b1, w2a0, w2a1;
    {
        const float* p1 = w1 + c * 32 + 8 * h;
        const float* p2 = w2 + c * 32 + 8 * h;
        #pragma unroll
        for (int j = 0; j < 8; ++j) {
            w1b0[j] = f2bf(p1[j]);  w1b1[j] = f2bf(p1[16 + j]);
            w2a0[j] = f2bf(p2[j]);  w2a1[j] = f2bf(p2[16 + j]);
        }
    }

    // Stage-2 C-init = bias. C/D: col=q=c, row=p=(reg&3)+8*(reg>>2)+4h,
    // y-index = p*32+q -> reg 4g+i corresponds to bias[(i+8g+4h)*32 + c].
    f32x16 yinit;
    #pragma unroll
    for (int g = 0; g < 4; ++g)
        #pragma unroll
        for (int i = 0; i < 4; ++i)
            yinit[4 * g + i] = bias[(i + 8 * g + 4 * h) * 32 + c];

    const int    gwave   = blockIdx.x * (TPB / 64) + wid;
    const size_t RSTRIDE = (size_t)NWAVES * 1024;   // row k -> row k+1 (per wave)

    const float* xp = x   + (size_t)gwave * 1024 + c * 32 + 8 * h;
    float*       op = out + (size_t)gwave * 1024;

    auto run_row = [&](const f32x4& xa, const f32x4& xb,
                       const f32x4& xc, const f32x4& xd, float* o) {
        // Stage-1 A (X_m): element[row=c][k=8h+j] = x[c*32 + 8h + j] (a1: +16)
        bf16x8 a0, a1;
        a0[0] = f2bf(xa[0]); a0[1] = f2bf(xa[1]); a0[2] = f2bf(xa[2]); a0[3] = f2bf(xa[3]);
        a0[4] = f2bf(xb[0]); a0[5] = f2bf(xb[1]); a0[6] = f2bf(xb[2]); a0[7] = f2bf(xb[3]);
        a1[0] = f2bf(xc[0]); a1[1] = f2bf(xc[1]); a1[2] = f2bf(xc[2]); a1[3] = f2bf(xc[3]);
        a1[4] = f2bf(xd[0]); a1[5] = f2bf(xd[1]); a1[6] = f2bf(xd[2]); a1[7] = f2bf(xd[3]);

        // Stage 1: T = X · W1^T  (K=32 as two K=16 MFMAs)
        f32x16 t = {};
        t = MFMA32(a0, w1b0, t);
        t = MFMA32(a1, w1b1, t);

        // In-register re-layout: lane (c,h') reg r holds T[(r&3)+8*(r>>2)+4h'][c].
        // Stage-2 B fragment needs tb0[j]=T[8h+j][c], tb1[j]=T[16+8h+j][c].
        // permlane32_swap(A,B): new_A = {A.lo31, B.lo31}, new_B = {A.hi31, B.hi31}
        // (semantics HW-verified in rounds 1/3: refcheck passed).
        uint32x2 r0 = __builtin_amdgcn_permlane32_swap(pk2(t[0],  t[1]),  pk2(t[4],  t[5]),  false, false);
        uint32x2 r1 = __builtin_amdgcn_permlane32_swap(pk2(t[2],  t[3]),  pk2(t[6],  t[7]),  false, false);
        uint32x2 r2 = __builtin_amdgcn_permlane32_swap(pk2(t[8],  t[9]),  pk2(t[12], t[13]), false, false);
        uint32x2 r3 = __builtin_amdgcn_permlane32_swap(pk2(t[10], t[11]), pk2(t[14], t[15]), false, false);
        uint32x4 utb0 = { r0[0], r1[0], r0[1], r1[1] };
        uint32x4 utb1 = { r2[0], r3[0], r2[1], r3[1] };

        // Stage 2: Y = W2 · T  (round-0 orientation), C init = bias
        f32x16 yv = yinit;
        yv = MFMA32(w2a0, __builtin_bit_cast(bf16x8, utb0), yv);
        yv = MFMA32(w2a1, __builtin_bit_cast(bf16x8, utb1), yv);

        // Epilogue: reg 4g+i -> out[(i+8g+4h)*32 + c]; each store instruction
        // covers q=0..31 contiguous dwords (2x 128B lines) -> coalesced.
        #pragma unroll
        for (int g = 0; g < 4; ++g)
            #pragma unroll
            for (int i = 0; i < 4; ++i)
                o[(i + 8 * g + 4 * h) * 32 + c] = yv[4 * g + i];
    };

    // x-row fragment loads: 4x float4 per lane at c*128B + h*32B (+0,+16,+64,+80)
    f32x4 xa = *(const f32x4*)(xp + 0);
    f32x4 xb = *(const f32x4*)(xp + 4);
    f32x4 xc = *(const f32x4*)(xp + 16);
    f32x4 xd = *(const f32x4*)(xp + 20);

    #pragma unroll 1
    for (int it = 0; it < RPW - 1; ++it) {
        const float* np = xp + RSTRIDE;          // prefetch next row first
        f32x4 na = *(const f32x4*)(np + 0);
        f32x4 nb = *(const f32x4*)(np + 4);
        f32x4 nc = *(const f32x4*)(np + 16);
        f32x4 nd = *(const f32x4*)(np + 20);
        run_row(xa, xb, xc, xd, op);
        xa = na; xb = nb; xc = nc; xd = nd;
        xp = np; op += RSTRIDE;
    }
    run_row(xa, xb, xc, xd, op);
}

extern "C" void kernel_launch(void* const* d_in, const int* in_sizes, int n_in,
                              void* d_out, int out_size, void* d_ws, size_t ws_size,
                              hipStream_t stream) {
    const float* x    = (const float*)d_in[0];
    const float* w1   = (const float*)d_in[1];
    const float* w2   = (const float*)d_in[2];
    const float* bias = (const float*)d_in[3];
    float* out        = (float*)d_out;
    kron_mlp_kernel<<<dim3(BLOCKS), dim3(TPB), 0, stream>>>(x, w1, w2, bias, out);
}